// Round 10
// baseline (235.743 us; speedup 1.0000x reference)
//
#include <hip/hip_runtime.h>
#include <stdint.h>

#define N_TOK 4096
#define DIM   1024          // K elements = K bytes in fp8
#define NCLS  32000
#define IGNIDX (-100)
#define BM 256
#define BN 256
#define BKB 128             // fp8 K-bytes per tile
#define NTN (NCLS / BN)     // 125 col-tiles
#define NTM (N_TOK / BM)    // 16 row-tiles
#define KT  (DIM / BKB)     // 8 K-tiles

typedef float   f32x4 __attribute__((ext_vector_type(4)));
typedef int     i32x4 __attribute__((ext_vector_type(4)));
typedef int     i32x8 __attribute__((ext_vector_type(8)));
typedef uint8_t u8;

#define VMCNT6 asm volatile("s_waitcnt vmcnt(6)" ::: "memory")
#define VMCNT4 asm volatile("s_waitcnt vmcnt(4)" ::: "memory")
#define VMCNT0 asm volatile("s_waitcnt vmcnt(0)" ::: "memory")
#define FENCE asm volatile("" ::: "memory")
#define BAR __builtin_amdgcn_s_barrier()

#define SCALE_ONE 0x7F7F7F7F   // e8m0 2^0 in every byte

// ---- fp32 -> fp8 e4m3 bulk convert (8 elems/thread) ----
__global__ void cvt_fp8(const float4* __restrict__ in, uint2* __restrict__ out, int n8) {
  int i = blockIdx.x * 256 + threadIdx.x;
  if (i >= n8) return;
  float4 a = in[2 * i], b = in[2 * i + 1];
  int lo = 0, hi = 0;
  lo = __builtin_amdgcn_cvt_pk_fp8_f32(a.x, a.y, lo, false);
  lo = __builtin_amdgcn_cvt_pk_fp8_f32(a.z, a.w, lo, true);
  hi = __builtin_amdgcn_cvt_pk_fp8_f32(b.x, b.y, hi, false);
  hi = __builtin_amdgcn_cvt_pk_fp8_f32(b.z, b.w, hi, true);
  out[i] = make_uint2((unsigned)lo, (unsigned)hi);
}

// ---- effective targets, ignore flags, divisor ----
__global__ void prep_targ(const int* __restrict__ targ, int* __restrict__ teff,
                          int* __restrict__ ign, float* __restrict__ divisor) {
  __shared__ int cnt[16];
  int local = 0;
  for (int i = threadIdx.x; i < N_TOK; i += 1024) {
    int t = targ[i];
    if (t != IGNIDX) local++;
    int pos = i & (N_TOK / 4 - 1);
    int te;
    if (pos < N_TOK / 4 - 1)      te = targ[i + 1];
    else if (i == N_TOK - 1)      te = IGNIDX;
    else                          te = targ[i + 2];
    ign[i] = (te == IGNIDX) ? 1 : 0;
    te = te < 0 ? 0 : (te > NCLS - 1 ? NCLS - 1 : te);
    teff[i] = te;
  }
#pragma unroll
  for (int d = 1; d < 64; d <<= 1) local += __shfl_xor(local, d);
  if ((threadIdx.x & 63) == 0) cnt[threadIdx.x >> 6] = local;
  __syncthreads();
  if (threadIdx.x == 0) {
    int t = 0;
    for (int i = 0; i < 16; i++) t += cnt[i];
    divisor[0] = (float)t;
  }
}

// LDS flat layout (bytes): A0 @0, A1 @32768, B0 @65536, B1 @98304.
// Staged 16B slot s of row r holds logical K-granule s ^ (r&7) (involution).

// direct global->LDS, 16B/lane, linear LDS dest (wave-uniform base)
#define STG(GSRC, LOFF) __builtin_amdgcn_global_load_lds(                  \
    (const __attribute__((address_space(1))) void*)(GSRC),                 \
    (__attribute__((address_space(3))) void*)&lds[LOFF], 16, 0, 0)

// one 16x16x128 fragment = 2 x ds_read_b128 (even/odd granule), 32-bit addrs.
// Plain HIP loads: compiler inserts fine-grained lgkmcnt(N) before each
// dependent MFMA, so the LDS drain overlaps the MFMA cluster (m97/m201
// mechanism). Do NOT add a wait-all lgkmcnt(0) here — that serializes
// the whole drain before the first MFMA (round-9's 2060-cyc phase).
#define FRAG(DST, EB, OB, IMM)                                             \
  { i32x4 _a = *(const i32x4*)&lds[(EB) + (IMM)];                          \
    i32x4 _b = *(const i32x4*)&lds[(OB) + (IMM)];                          \
    DST[0] = _a[0]; DST[1] = _a[1]; DST[2] = _a[2]; DST[3] = _a[3];        \
    DST[4] = _b[0]; DST[5] = _b[1]; DST[6] = _b[2]; DST[7] = _b[3]; }

#define LOADA(MH, EB, OB)                 \
  FRAG(aF[0], EB, OB, (MH)*8192 + 0)      \
  FRAG(aF[1], EB, OB, (MH)*8192 + 2048)   \
  FRAG(aF[2], EB, OB, (MH)*8192 + 4096)   \
  FRAG(aF[3], EB, OB, (MH)*8192 + 6144)

#define LOADB(DST, NH, EB, OB)            \
  FRAG(DST[0], EB, OB, (NH)*4096 + 0)     \
  FRAG(DST[1], EB, OB, (NH)*4096 + 2048)

#define DOMFMA(MH, NH, BF)                                                  \
  __builtin_amdgcn_s_setprio(1);                                            \
  _Pragma("unroll")                                                         \
  for (int mm = 0; mm < 4; mm++)                                            \
    _Pragma("unroll")                                                       \
    for (int nn = 0; nn < 2; nn++)                                          \
      acc[(MH)*4 + mm][(NH)*2 + nn] =                                       \
          __builtin_amdgcn_mfma_scale_f32_16x16x128_f8f6f4(                 \
              aF[mm], BF[nn], acc[(MH)*4 + mm][(NH)*2 + nn],                \
              0, 0, 0, SCALE_ONE, 0, SCALE_ONE);                            \
  __builtin_amdgcn_s_setprio(0);

// ---- fused 256x256 MX-fp8 pipelined GEMM + per-tile sum(exp) partials ----
// Schedule = round 7/9 (8/4/8/4 reads, carried bF0, vmcnt6 chain), minus the
// per-phase wait-all lgkmcnt(0)+sched_barrier (round-10 change).
__launch_bounds__(512, 2)
__global__ void gemm_lse(const u8* __restrict__ Xf8, const u8* __restrict__ Wf8,
                         const int* __restrict__ teff, float* __restrict__ gt,
                         float* __restrict__ partial) {
  __shared__ __align__(16) u8 lds[131072];

  const int tid = threadIdx.x;
  const int w = tid >> 6, l = tid & 63;
  const int wm = w >> 2, wn = w & 3;          // 2 x 4 wave grid
  const int hi = l >> 4, lo = l & 15;
  const int q = l & 7;

  // XCD-chunked bijective swizzle (2000 % 8 == 0)
  const int bid = blockIdx.x;
  const int wg = (bid & 7) * (NTM * NTN / 8) + (bid >> 3);
  const int bx = wg & (NTM - 1), by = wg >> 4;
  const int rowBase = bx * BM, colBase = by * BN;

  // uniform global bases (SGPR) + invariant per-lane 32-bit offsets
  const u8* pA = Xf8 + (size_t)rowBase * DIM;
  const u8* pB = Wf8 + (size_t)colBase * DIM;
  const int lr = l >> 3, lg = (l & 7) ^ lr;
  const int voffA = (w * 8 + lr) * DIM + lg * 16;
  const int voffB = ((w >> 2) * 64 + (w & 3) * 8 + lr) * DIM + lg * 16;
  // wave-uniform LDS staging bases
  const int ldsAb = w * 1024;
  const int ldsBb = 65536 + (w >> 2) * 8192 + (w & 3) * 1024;

  // per-lane fragment-read bases (32-bit LDS byte offsets)
  const int slotE = (((hi * 2) ^ q)) << 4;
  const int aE = (wm * 128 + lo) * BKB + slotE;
  const int aO = aE ^ 16;
  const int bE = 65536 + (wn * 64 + lo) * BKB + slotE;
  const int bO = bE ^ 16;

  f32x4 acc[8][4] = {};

  // ---- prologue: Ah0(0), Bh0(0), Ah1(0), Bh1(0), Ah0(1), Bh0(1) = 12 loads ----
  STG(pA + voffA, ldsAb);                  STG(pA + 131072 + voffA, ldsAb + 16384);
  STG(pB + voffB, ldsBb);                  STG(pB + 131072 + voffB, ldsBb + 16384);
  STG(pA + 65536 + voffA, ldsAb + 8192);   STG(pA + 196608 + voffA, ldsAb + 24576);
  STG(pB + 32768 + voffB, ldsBb + 4096);   STG(pB + 163840 + voffB, ldsBb + 20480);
  STG(pA + BKB + voffA, ldsAb + 32768);    STG(pA + 131072 + BKB + voffA, ldsAb + 49152);
  STG(pB + BKB + voffB, ldsBb + 32768);    STG(pB + 131072 + BKB + voffB, ldsBb + 49152);
  VMCNT4;  // tile-0 regions complete; Ah0(1)/Bh0(1) may linger
  FENCE; BAR;

  i32x8 aF[4], bF0[2], bF1[2];
  LOADB(bF0, 0, bE, bO)    // preload bF0 for tile 0 (buffer 0)

#pragma unroll 1
  for (int t = 0; t < KT; t++) {
    const int bs  = (t & 1) << 15;          // current buffer byte offset
    const int bn_ = bs ^ 32768;             // other buffer
    const int aEc = aE + bs, aOc = aO + bs;
    const int bEc = bE + bs, bOc = bO + bs;
    const int bEn = bE + bn_, bOn = bO + bn_;
    const int k1 = ((t + 1) & 7) * BKB;     // uniform (SALU)
    const int k2 = ((t + 2) & 7) * BKB;

    // ---- p0: loadA h0 (8); q(0,0) w/ carried bF0; stage Bh1(t+1)->other ----
    LOADA(0, aEc, aOc)
    STG(pB + (k1 + 32768) + voffB, ldsBb + 4096 + bn_);
    STG(pB + (k1 + 163840) + voffB, ldsBb + 20480 + bn_);
    FENCE; BAR;
    DOMFMA(0, 0, bF0)
    VMCNT6; FENCE; BAR;

    // ---- p1: loadB h1 (4); q(0,1); stage Ah1(t+1)->other ----
    LOADB(bF1, 1, bEc, bOc)
    STG(pA + (k1 + 65536) + voffA, ldsAb + 8192 + bn_);
    STG(pA + (k1 + 196608) + voffA, ldsAb + 24576 + bn_);
    FENCE; BAR;
    DOMFMA(0, 1, bF1)
    VMCNT6; FENCE; BAR;

    // ---- p2: loadA h1 (8); q(1,0) w/ bF0; stage Ah0(t+2)->CURRENT ----
    LOADA(1, aEc, aOc)
    STG(pA + k2 + voffA, ldsAb + bs);
    STG(pA + (k2 + 131072) + voffA, ldsAb + 16384 + bs);
    FENCE; BAR;
    DOMFMA(1, 0, bF0)
    VMCNT6; FENCE; BAR;

    // ---- p3: preload bF0(t+1) from OTHER buf (4); q(1,1); stage Bh0(t+2)->CURRENT ----
    LOADB(bF0, 0, bEn, bOn)
    STG(pB + k2 + voffB, ldsBb + bs);
    STG(pB + (k2 + 131072) + voffB, ldsBb + 16384 + bs);
    FENCE; BAR;
    DOMFMA(1, 1, bF1)
    VMCNT6; FENCE; BAR;
  }

  // drain in-flight wrap stages before reusing LDS as reduction scratch
  VMCNT0; FENCE; BAR;

  // ---- epilogue: per-row sum(exp) over this 256-col tile + gt extraction ----
  float* red = (float*)lds;
#pragma unroll
  for (int m = 0; m < 8; m++) {
#pragma unroll
    for (int j = 0; j < 4; j++) {
      const int rloc = wm * 128 + m * 16 + hi * 4 + j;
      const int gr = rowBase + rloc;
      const int te = teff[gr];
      float s = 0.f;
#pragma unroll
      for (int n = 0; n < 4; n++) {
        float v = acc[m][n][j];
        const int gc = colBase + wn * 64 + n * 16 + lo;
        if (te == gc) gt[gr] = v;
        s += __expf(v);
      }
#pragma unroll
      for (int d = 1; d < 16; d <<= 1) s += __shfl_xor(s, d);
      if (lo == 0) red[wn * 256 + rloc] = s;
    }
  }
  __syncthreads();
  if (tid < 256) {
    float S = red[tid] + red[256 + tid] + red[512 + tid] + red[768 + tid];
    partial[(size_t)(rowBase + tid) * NTN + by] = S;
  }
}

// ---- combine 125 tile partials per row -> per-token loss ----
__global__ void reduce_lse(const float* __restrict__ partial, const float* __restrict__ gt,
                           const int* __restrict__ ign, const float* __restrict__ divisor,
                           float* __restrict__ pertok) {
  int r = blockIdx.x * 4 + (threadIdx.x >> 6);
  int l = threadIdx.x & 63;
  float S = 0.f;
  for (int p = l; p < NTN; p += 64) S += partial[(size_t)r * NTN + p];
#pragma unroll
  for (int d = 1; d < 64; d <<= 1) S += __shfl_xor(S, d);
  if (l == 0) {
    float lse = __logf(S);
    pertok[r] = ign[r] ? 0.f : (lse - gt[r]) / divisor[0];
  }
}

// ---- deterministic final sum ----
__global__ void final_sum(const float* __restrict__ pertok, float* __restrict__ out) {
  __shared__ float red[16];
  float s = 0.f;
  for (int i = threadIdx.x; i < N_TOK; i += 1024) s += pertok[i];
#pragma unroll
  for (int d = 1; d < 64; d <<= 1) s += __shfl_xor(s, d);
  if ((threadIdx.x & 63) == 0) red[threadIdx.x >> 6] = s;
  __syncthreads();
  if (threadIdx.x == 0) {
    float t = 0.f;
    for (int i = 0; i < 16; i++) t += red[i];
    out[0] = t;
  }
}

extern "C" void kernel_launch(void* const* d_in, const int* in_sizes, int n_in,
                              void* d_out, int out_size, void* d_ws, size_t ws_size,
                              hipStream_t stream) {
  const float* x = (const float*)d_in[0];       // [4096,1024] f32
  const float* w = (const float*)d_in[1];       // [32000,1024] f32
  const int* targ = (const int*)d_in[2];        // [4096] int
  float* out = (float*)d_out;

  char* ws = (char*)d_ws;
  u8*    Xf8     = (u8*)(ws);                      // 4,194,304 B
  u8*    Wf8     = (u8*)(ws + 4194304);            // 32,768,000 B
  float* partial = (float*)(ws + 36962304);        // 2,048,000 B
  float* gt      = (float*)(ws + 39010304);        // 16,384 B
  int*   teff    = (int*)(ws + 39026688);          // 16,384 B
  int*   ign     = (int*)(ws + 39043072);          // 16,384 B
  float* divisor = (float*)(ws + 39059456);        // 256 B
  float* pertok  = (float*)(ws + 39059712);        // 16,384 B

  {
    int n8 = N_TOK * DIM / 8;                      // 524288
    cvt_fp8<<<(n8 + 255) / 256, 256, 0, stream>>>((const float4*)x, (uint2*)Xf8, n8);
  }
  {
    int n8 = NCLS * DIM / 8;                       // 4,096,000
    cvt_fp8<<<(n8 + 255) / 256, 256, 0, stream>>>((const float4*)w, (uint2*)Wf8, n8);
  }
  prep_targ<<<1, 1024, 0, stream>>>(targ, teff, ign, divisor);

  gemm_lse<<<NTM * NTN, 512, 0, stream>>>(Xf8, Wf8, teff, gt, partial);  // 2000 blocks

  reduce_lse<<<N_TOK / 4, 256, 0, stream>>>(partial, gt, ign, divisor, pertok);
  final_sum<<<1, 1024, 0, stream>>>(pertok, out);
}

// Round 11
// 229.144 us; speedup vs baseline: 1.0288x; 1.0288x over previous
//
#include <hip/hip_runtime.h>
#include <stdint.h>

#define N_TOK 4096
#define DIM   1024          // K elements = K bytes in fp8
#define NCLS  32000
#define IGNIDX (-100)
#define BM 256
#define BN 256
#define BKB 128             // fp8 K-bytes per tile
#define NTN (NCLS / BN)     // 125 col-tiles
#define NTM (N_TOK / BM)    // 16 row-tiles
#define KT  (DIM / BKB)     // 8 K-tiles

typedef float   f32x4 __attribute__((ext_vector_type(4)));
typedef int     i32x4 __attribute__((ext_vector_type(4)));
typedef int     i32x8 __attribute__((ext_vector_type(8)));
typedef uint8_t u8;

#define VMCNT4 asm volatile("s_waitcnt vmcnt(4)" ::: "memory")
#define VMCNT0 asm volatile("s_waitcnt vmcnt(0)" ::: "memory")
#define FENCE asm volatile("" ::: "memory")
#define BAR __builtin_amdgcn_s_barrier()

#define SCALE_ONE 0x7F7F7F7F   // e8m0 2^0 in every byte

// ---- fp32 -> fp8 e4m3 bulk convert (8 elems/thread) ----
__global__ void cvt_fp8(const float4* __restrict__ in, uint2* __restrict__ out, int n8) {
  int i = blockIdx.x * 256 + threadIdx.x;
  if (i >= n8) return;
  float4 a = in[2 * i], b = in[2 * i + 1];
  int lo = 0, hi = 0;
  lo = __builtin_amdgcn_cvt_pk_fp8_f32(a.x, a.y, lo, false);
  lo = __builtin_amdgcn_cvt_pk_fp8_f32(a.z, a.w, lo, true);
  hi = __builtin_amdgcn_cvt_pk_fp8_f32(b.x, b.y, hi, false);
  hi = __builtin_amdgcn_cvt_pk_fp8_f32(b.z, b.w, hi, true);
  out[i] = make_uint2((unsigned)lo, (unsigned)hi);
}

// ---- effective targets, ignore flags, divisor ----
__global__ void prep_targ(const int* __restrict__ targ, int* __restrict__ teff,
                          int* __restrict__ ign, float* __restrict__ divisor) {
  __shared__ int cnt[16];
  int local = 0;
  for (int i = threadIdx.x; i < N_TOK; i += 1024) {
    int t = targ[i];
    if (t != IGNIDX) local++;
    int pos = i & (N_TOK / 4 - 1);
    int te;
    if (pos < N_TOK / 4 - 1)      te = targ[i + 1];
    else if (i == N_TOK - 1)      te = IGNIDX;
    else                          te = targ[i + 2];
    ign[i] = (te == IGNIDX) ? 1 : 0;
    te = te < 0 ? 0 : (te > NCLS - 1 ? NCLS - 1 : te);
    teff[i] = te;
  }
#pragma unroll
  for (int d = 1; d < 64; d <<= 1) local += __shfl_xor(local, d);
  if ((threadIdx.x & 63) == 0) cnt[threadIdx.x >> 6] = local;
  __syncthreads();
  if (threadIdx.x == 0) {
    int t = 0;
    for (int i = 0; i < 16; i++) t += cnt[i];
    divisor[0] = (float)t;
  }
}

// LDS flat layout (bytes): A0 @0, A1 @32768, B0 @65536, B1 @98304.
// Staged 16B slot s of row r holds logical K-granule s ^ (r&7) (involution).

// direct global->LDS, 16B/lane, linear LDS dest (wave-uniform base)
#define STG(GSRC, LOFF) __builtin_amdgcn_global_load_lds(                  \
    (const __attribute__((address_space(1))) void*)(GSRC),                 \
    (__attribute__((address_space(3))) void*)&lds[LOFF], 16, 0, 0)

// one 16x16x128 fragment = 2 x ds_read_b128 (even/odd granule), 32-bit addrs
#define FRAG(DST, EB, OB, IMM)                                             \
  { i32x4 _a = *(const i32x4*)&lds[(EB) + (IMM)];                          \
    i32x4 _b = *(const i32x4*)&lds[(OB) + (IMM)];                          \
    DST[0] = _a[0]; DST[1] = _a[1]; DST[2] = _a[2]; DST[3] = _a[3];        \
    DST[4] = _b[0]; DST[5] = _b[1]; DST[6] = _b[2]; DST[7] = _b[3]; }

#define LOADA(MH, EB, OB)                 \
  FRAG(aF[0], EB, OB, (MH)*8192 + 0)      \
  FRAG(aF[1], EB, OB, (MH)*8192 + 2048)   \
  FRAG(aF[2], EB, OB, (MH)*8192 + 4096)   \
  FRAG(aF[3], EB, OB, (MH)*8192 + 6144)

#define LOADB(DST, NH, EB, OB)            \
  FRAG(DST[0], EB, OB, (NH)*4096 + 0)     \
  FRAG(DST[1], EB, OB, (NH)*4096 + 2048)

// 16 MFMA = one m-half x full n (q(MH,0) + q(MH,1)), single setprio region
#define DOMFMA2(MH)                                                         \
  __builtin_amdgcn_s_setprio(1);                                            \
  _Pragma("unroll")                                                         \
  for (int mm = 0; mm < 4; mm++) {                                          \
    _Pragma("unroll")                                                       \
    for (int nn = 0; nn < 2; nn++)                                          \
      acc[(MH)*4 + mm][nn] =                                                \
          __builtin_amdgcn_mfma_scale_f32_16x16x128_f8f6f4(                 \
              aF[mm], bF0[nn], acc[(MH)*4 + mm][nn],                        \
              0, 0, 0, SCALE_ONE, 0, SCALE_ONE);                            \
    _Pragma("unroll")                                                       \
    for (int nn = 0; nn < 2; nn++)                                          \
      acc[(MH)*4 + mm][2 + nn] =                                            \
          __builtin_amdgcn_mfma_scale_f32_16x16x128_f8f6f4(                 \
              aF[mm], bF1[nn], acc[(MH)*4 + mm][2 + nn],                    \
              0, 0, 0, SCALE_ONE, 0, SCALE_ONE);                            \
  }                                                                         \
  __builtin_amdgcn_s_setprio(0);

// ---- fused 256x256 MX-fp8 GEMM + per-tile sum(exp) partials ----
// Round-11: 2 fat phases per K-tile, ONE barrier each (was 4 phases x 2
// barriers). Hazard chain: every region's last-read MFMA completes (via its
// own lgkm dep) before its reader passes the phase-end barrier; the re-stage
// of that region is issued only after that barrier. Staged data is awaited
// by uniform vmcnt(4) one-phase-later + barrier before its first read.
__launch_bounds__(512, 2)
__global__ void gemm_lse(const u8* __restrict__ Xf8, const u8* __restrict__ Wf8,
                         const int* __restrict__ teff, float* __restrict__ gt,
                         float* __restrict__ partial) {
  __shared__ __align__(16) u8 lds[131072];

  const int tid = threadIdx.x;
  const int w = tid >> 6, l = tid & 63;
  const int wm = w >> 2, wn = w & 3;          // 2 x 4 wave grid
  const int hi = l >> 4, lo = l & 15;
  const int q = l & 7;

  // XCD-chunked bijective swizzle (2000 % 8 == 0)
  const int bid = blockIdx.x;
  const int wg = (bid & 7) * (NTM * NTN / 8) + (bid >> 3);
  const int bx = wg & (NTM - 1), by = wg >> 4;
  const int rowBase = bx * BM, colBase = by * BN;

  // uniform global bases (SGPR) + invariant per-lane 32-bit offsets
  const u8* pA = Xf8 + (size_t)rowBase * DIM;
  const u8* pB = Wf8 + (size_t)colBase * DIM;
  const int lr = l >> 3, lg = (l & 7) ^ lr;
  const int voffA = (w * 8 + lr) * DIM + lg * 16;
  const int voffB = ((w >> 2) * 64 + (w & 3) * 8 + lr) * DIM + lg * 16;
  // wave-uniform LDS staging bases
  const int ldsAb = w * 1024;
  const int ldsBb = 65536 + (w >> 2) * 8192 + (w & 3) * 1024;

  // per-lane fragment-read bases (32-bit LDS byte offsets)
  const int slotE = (((hi * 2) ^ q)) << 4;
  const int aE = (wm * 128 + lo) * BKB + slotE;
  const int aO = aE ^ 16;
  const int bE = 65536 + (wn * 64 + lo) * BKB + slotE;
  const int bO = bE ^ 16;

  f32x4 acc[8][4] = {};

  // ---- prologue: Ah0(0), Bh0(0), Ah1(0), Bh1(0), Ah0(1), Bh0(1) = 12 loads ----
  STG(pA + voffA, ldsAb);                  STG(pA + 131072 + voffA, ldsAb + 16384);
  STG(pB + voffB, ldsBb);                  STG(pB + 131072 + voffB, ldsBb + 16384);
  STG(pA + 65536 + voffA, ldsAb + 8192);   STG(pA + 196608 + voffA, ldsAb + 24576);
  STG(pB + 32768 + voffB, ldsBb + 4096);   STG(pB + 163840 + voffB, ldsBb + 20480);
  STG(pA + BKB + voffA, ldsAb + 32768);    STG(pA + 131072 + BKB + voffA, ldsAb + 49152);
  STG(pB + BKB + voffB, ldsBb + 32768);    STG(pB + 131072 + BKB + voffB, ldsBb + 49152);
  VMCNT4;  // tile-0 regions complete; Ah0(1)/Bh0(1) may linger
  FENCE; BAR;

  i32x8 aF[4], bF0[2], bF1[2];

#pragma unroll 1
  for (int t = 0; t < KT; t++) {
    const int bs  = (t & 1) << 15;          // current buffer byte offset
    const int bn_ = bs ^ 32768;             // other buffer
    const int aEc = aE + bs, aOc = aO + bs;
    const int bEc = bE + bs, bOc = bO + bs;
    const int k1 = ((t + 1) & 7) * BKB;     // uniform (SALU)
    const int k2 = ((t + 2) & 7) * BKB;

    // ---- alpha: read Ah0+Bh0+Bh1 (16); stage Bh1,Ah1(t+1)->other; 16 MFMA ----
    LOADA(0, aEc, aOc)
    LOADB(bF0, 0, bEc, bOc)
    LOADB(bF1, 1, bEc, bOc)
    STG(pB + (k1 + 32768) + voffB, ldsBb + 4096 + bn_);
    STG(pB + (k1 + 163840) + voffB, ldsBb + 20480 + bn_);
    STG(pA + (k1 + 65536) + voffA, ldsAb + 8192 + bn_);
    STG(pA + (k1 + 196608) + voffA, ldsAb + 24576 + bn_);
    DOMFMA2(0)
    VMCNT4; FENCE; BAR;

    // ---- beta: read Ah1 (8); stage Ah0,Bh0(t+2)->cur; 16 MFMA (reuse bF0/bF1) ----
    LOADA(1, aEc, aOc)
    STG(pA + k2 + voffA, ldsAb + bs);
    STG(pA + (k2 + 131072) + voffA, ldsAb + 16384 + bs);
    STG(pB + k2 + voffB, ldsBb + bs);
    STG(pB + (k2 + 131072) + voffB, ldsBb + 16384 + bs);
    DOMFMA2(1)
    VMCNT4; FENCE; BAR;
  }

  // drain in-flight wrap stages before reusing LDS as reduction scratch
  VMCNT0; FENCE; BAR;

  // ---- epilogue: per-row sum(exp) over this 256-col tile + gt extraction ----
  float* red = (float*)lds;
#pragma unroll
  for (int m = 0; m < 8; m++) {
#pragma unroll
    for (int j = 0; j < 4; j++) {
      const int rloc = wm * 128 + m * 16 + hi * 4 + j;
      const int gr = rowBase + rloc;
      const int te = teff[gr];
      float s = 0.f;
#pragma unroll
      for (int n = 0; n < 4; n++) {
        float v = acc[m][n][j];
        const int gc = colBase + wn * 64 + n * 16 + lo;
        if (te == gc) gt[gr] = v;
        s += __expf(v);
      }
#pragma unroll
      for (int d = 1; d < 16; d <<= 1) s += __shfl_xor(s, d);
      if (lo == 0) red[wn * 256 + rloc] = s;
    }
  }
  __syncthreads();
  if (tid < 256) {
    float S = red[tid] + red[256 + tid] + red[512 + tid] + red[768 + tid];
    partial[(size_t)(rowBase + tid) * NTN + by] = S;
  }
}

// ---- combine 125 tile partials per row -> per-token loss ----
__global__ void reduce_lse(const float* __restrict__ partial, const float* __restrict__ gt,
                           const int* __restrict__ ign, const float* __restrict__ divisor,
                           float* __restrict__ pertok) {
  int r = blockIdx.x * 4 + (threadIdx.x >> 6);
  int l = threadIdx.x & 63;
  float S = 0.f;
  for (int p = l; p < NTN; p += 64) S += partial[(size_t)r * NTN + p];
#pragma unroll
  for (int d = 1; d < 64; d <<= 1) S += __shfl_xor(S, d);
  if (l == 0) {
    float lse = __logf(S);
    pertok[r] = ign[r] ? 0.f : (lse - gt[r]) / divisor[0];
  }
}

// ---- deterministic final sum ----
__global__ void final_sum(const float* __restrict__ pertok, float* __restrict__ out) {
  __shared__ float red[16];
  float s = 0.f;
  for (int i = threadIdx.x; i < N_TOK; i += 1024) s += pertok[i];
#pragma unroll
  for (int d = 1; d < 64; d <<= 1) s += __shfl_xor(s, d);
  if ((threadIdx.x & 63) == 0) red[threadIdx.x >> 6] = s;
  __syncthreads();
  if (threadIdx.x == 0) {
    float t = 0.f;
    for (int i = 0; i < 16; i++) t += red[i];
    out[0] = t;
  }
}

extern "C" void kernel_launch(void* const* d_in, const int* in_sizes, int n_in,
                              void* d_out, int out_size, void* d_ws, size_t ws_size,
                              hipStream_t stream) {
  const float* x = (const float*)d_in[0];       // [4096,1024] f32
  const float* w = (const float*)d_in[1];       // [32000,1024] f32
  const int* targ = (const int*)d_in[2];        // [4096] int
  float* out = (float*)d_out;

  char* ws = (char*)d_ws;
  u8*    Xf8     = (u8*)(ws);                      // 4,194,304 B
  u8*    Wf8     = (u8*)(ws + 4194304);            // 32,768,000 B
  float* partial = (float*)(ws + 36962304);        // 2,048,000 B
  float* gt      = (float*)(ws + 39010304);        // 16,384 B
  int*   teff    = (int*)(ws + 39026688);          // 16,384 B
  int*   ign     = (int*)(ws + 39043072);          // 16,384 B
  float* divisor = (float*)(ws + 39059456);        // 256 B
  float* pertok  = (float*)(ws + 39059712);        // 16,384 B

  {
    int n8 = N_TOK * DIM / 8;                      // 524288
    cvt_fp8<<<(n8 + 255) / 256, 256, 0, stream>>>((const float4*)x, (uint2*)Xf8, n8);
  }
  {
    int n8 = NCLS * DIM / 8;                       // 4,096,000
    cvt_fp8<<<(n8 + 255) / 256, 256, 0, stream>>>((const float4*)w, (uint2*)Wf8, n8);
  }
  prep_targ<<<1, 1024, 0, stream>>>(targ, teff, ign, divisor);

  gemm_lse<<<NTM * NTN, 512, 0, stream>>>(Xf8, Wf8, teff, gt, partial);  // 2000 blocks

  reduce_lse<<<N_TOK / 4, 256, 0, stream>>>(partial, gt, ign, divisor, pertok);
  final_sum<<<1, 1024, 0, stream>>>(pertok, out);
}

// Round 12
// 228.611 us; speedup vs baseline: 1.0312x; 1.0023x over previous
//
#include <hip/hip_runtime.h>
#include <stdint.h>

#define N_TOK 4096
#define DIM   1024          // K elements = K bytes in fp8
#define NCLS  32000
#define IGNIDX (-100)
#define BM 256
#define BN 256
#define BKB 128             // fp8 K-bytes per tile
#define NTN (NCLS / BN)     // 125 col-tiles
#define NTM (N_TOK / BM)    // 16 row-tiles
#define KT  (DIM / BKB)     // 8 K-tiles

typedef float   f32x4 __attribute__((ext_vector_type(4)));
typedef int     i32x4 __attribute__((ext_vector_type(4)));
typedef int     i32x8 __attribute__((ext_vector_type(8)));
typedef uint8_t u8;

#define VMCNT0 asm volatile("s_waitcnt vmcnt(0)" ::: "memory")
#define FENCE asm volatile("" ::: "memory")
#define BAR __builtin_amdgcn_s_barrier()

#define SCALE_ONE 0x7F7F7F7F   // e8m0 2^0 in every byte

// ---- fp32 -> fp8 e4m3 bulk convert (8 elems/thread) ----
__global__ void cvt_fp8(const float4* __restrict__ in, uint2* __restrict__ out, int n8) {
  int i = blockIdx.x * 256 + threadIdx.x;
  if (i >= n8) return;
  float4 a = in[2 * i], b = in[2 * i + 1];
  int lo = 0, hi = 0;
  lo = __builtin_amdgcn_cvt_pk_fp8_f32(a.x, a.y, lo, false);
  lo = __builtin_amdgcn_cvt_pk_fp8_f32(a.z, a.w, lo, true);
  hi = __builtin_amdgcn_cvt_pk_fp8_f32(b.x, b.y, hi, false);
  hi = __builtin_amdgcn_cvt_pk_fp8_f32(b.z, b.w, hi, true);
  out[i] = make_uint2((unsigned)lo, (unsigned)hi);
}

// ---- effective targets, ignore flags, divisor ----
__global__ void prep_targ(const int* __restrict__ targ, int* __restrict__ teff,
                          int* __restrict__ ign, float* __restrict__ divisor) {
  __shared__ int cnt[16];
  int local = 0;
  for (int i = threadIdx.x; i < N_TOK; i += 1024) {
    int t = targ[i];
    if (t != IGNIDX) local++;
    int pos = i & (N_TOK / 4 - 1);
    int te;
    if (pos < N_TOK / 4 - 1)      te = targ[i + 1];
    else if (i == N_TOK - 1)      te = IGNIDX;
    else                          te = targ[i + 2];
    ign[i] = (te == IGNIDX) ? 1 : 0;
    te = te < 0 ? 0 : (te > NCLS - 1 ? NCLS - 1 : te);
    teff[i] = te;
  }
#pragma unroll
  for (int d = 1; d < 64; d <<= 1) local += __shfl_xor(local, d);
  if ((threadIdx.x & 63) == 0) cnt[threadIdx.x >> 6] = local;
  __syncthreads();
  if (threadIdx.x == 0) {
    int t = 0;
    for (int i = 0; i < 16; i++) t += cnt[i];
    divisor[0] = (float)t;
  }
}

// LDS flat layout (bytes): A0 @0, A1 @32768, B0 @65536, B1 @98304.
// Staged 16B slot s of row r holds logical K-granule s ^ (r&7) (involution).

// direct global->LDS, 16B/lane, linear LDS dest (wave-uniform base)
#define STG(GSRC, LOFF) __builtin_amdgcn_global_load_lds(                  \
    (const __attribute__((address_space(1))) void*)(GSRC),                 \
    (__attribute__((address_space(3))) void*)&lds[LOFF], 16, 0, 0)

// one 16x16x128 fragment = 2 x ds_read_b128 (even/odd granule), 32-bit addrs
#define FRAG(DST, EB, OB, IMM)                                             \
  { i32x4 _a = *(const i32x4*)&lds[(EB) + (IMM)];                          \
    i32x4 _b = *(const i32x4*)&lds[(OB) + (IMM)];                          \
    DST[0] = _a[0]; DST[1] = _a[1]; DST[2] = _a[2]; DST[3] = _a[3];        \
    DST[4] = _b[0]; DST[5] = _b[1]; DST[6] = _b[2]; DST[7] = _b[3]; }

#define LOADA(MH, EB, OB)                 \
  FRAG(aF[0], EB, OB, (MH)*8192 + 0)      \
  FRAG(aF[1], EB, OB, (MH)*8192 + 2048)   \
  FRAG(aF[2], EB, OB, (MH)*8192 + 4096)   \
  FRAG(aF[3], EB, OB, (MH)*8192 + 6144)

#define LOADB(DST, NH, EB, OB)            \
  FRAG(DST[0], EB, OB, (NH)*4096 + 0)     \
  FRAG(DST[1], EB, OB, (NH)*4096 + 2048)

// 16 MFMA = one m-half x full n (q(MH,0) + q(MH,1)), single setprio region
#define DOMFMA2(MH)                                                         \
  __builtin_amdgcn_s_setprio(1);                                            \
  _Pragma("unroll")                                                         \
  for (int mm = 0; mm < 4; mm++) {                                          \
    _Pragma("unroll")                                                       \
    for (int nn = 0; nn < 2; nn++)                                          \
      acc[(MH)*4 + mm][nn] =                                                \
          __builtin_amdgcn_mfma_scale_f32_16x16x128_f8f6f4(                 \
              aF[mm], bF0[nn], acc[(MH)*4 + mm][nn],                        \
              0, 0, 0, SCALE_ONE, 0, SCALE_ONE);                            \
    _Pragma("unroll")                                                       \
    for (int nn = 0; nn < 2; nn++)                                          \
      acc[(MH)*4 + mm][2 + nn] =                                            \
          __builtin_amdgcn_mfma_scale_f32_16x16x128_f8f6f4(                 \
              aF[mm], bF1[nn], acc[(MH)*4 + mm][2 + nn],                    \
              0, 0, 0, SCALE_ONE, 0, SCALE_ONE);                            \
  }                                                                         \
  __builtin_amdgcn_s_setprio(0);

// ---- fused 256x256 MX-fp8 GEMM + per-tile sum(exp) partials ----
// Round-12: ONE phase + ONE barrier per K-tile. All 4 regions of tile t+1
// staged into the OTHER buffer (distance-1 prefetch; L2-resident panels,
// ~300cy latency hidden under ~3000cy of MFMA). Every ds_read is consumed
// by an in-tile MFMA (so lgkm-retired before the barrier); stage writes only
// touch the other buffer -> no in-place WAR. vmcnt(0) once per tile.
__launch_bounds__(512, 2)
__global__ void gemm_lse(const u8* __restrict__ Xf8, const u8* __restrict__ Wf8,
                         const int* __restrict__ teff, float* __restrict__ gt,
                         float* __restrict__ partial) {
  __shared__ __align__(16) u8 lds[131072];

  const int tid = threadIdx.x;
  const int w = tid >> 6, l = tid & 63;
  const int wm = w >> 2, wn = w & 3;          // 2 x 4 wave grid
  const int hi = l >> 4, lo = l & 15;
  const int q = l & 7;

  // XCD-chunked bijective swizzle (2000 % 8 == 0)
  const int bid = blockIdx.x;
  const int wg = (bid & 7) * (NTM * NTN / 8) + (bid >> 3);
  const int bx = wg & (NTM - 1), by = wg >> 4;
  const int rowBase = bx * BM, colBase = by * BN;

  // uniform global bases (SGPR) + invariant per-lane 32-bit offsets
  const u8* pA = Xf8 + (size_t)rowBase * DIM;
  const u8* pB = Wf8 + (size_t)colBase * DIM;
  const int lr = l >> 3, lg = (l & 7) ^ lr;
  const int voffA = (w * 8 + lr) * DIM + lg * 16;
  const int voffB = ((w >> 2) * 64 + (w & 3) * 8 + lr) * DIM + lg * 16;
  // wave-uniform LDS staging bases
  const int ldsAb = w * 1024;
  const int ldsBb = 65536 + (w >> 2) * 8192 + (w & 3) * 1024;

  // per-lane fragment-read bases (32-bit LDS byte offsets)
  const int slotE = (((hi * 2) ^ q)) << 4;
  const int aE = (wm * 128 + lo) * BKB + slotE;
  const int aO = aE ^ 16;
  const int bE = 65536 + (wn * 64 + lo) * BKB + slotE;
  const int bO = bE ^ 16;

  f32x4 acc[8][4] = {};

  // ---- prologue: stage all of tile 0 -> buf0 (8 loads), full drain ----
  STG(pA + voffA, ldsAb);                  STG(pA + 131072 + voffA, ldsAb + 16384);
  STG(pA + 65536 + voffA, ldsAb + 8192);   STG(pA + 196608 + voffA, ldsAb + 24576);
  STG(pB + voffB, ldsBb);                  STG(pB + 131072 + voffB, ldsBb + 16384);
  STG(pB + 32768 + voffB, ldsBb + 4096);   STG(pB + 163840 + voffB, ldsBb + 20480);
  VMCNT0; FENCE; BAR;

  i32x8 aF[4], bF0[2], bF1[2];

#pragma unroll 1
  for (int t = 0; t < KT; t++) {
    const int bs  = (t & 1) << 15;          // current buffer byte offset
    const int bn_ = bs ^ 32768;             // other buffer
    const int aEc = aE + bs, aOc = aO + bs;
    const int bEc = bE + bs, bOc = bO + bs;
    const int k1 = ((t + 1) & 7) * BKB;     // uniform (SALU)

    // stage tile t+1 (all 4 regions) -> other buffer; latency hides under MFMAs
    STG(pA + k1 + voffA, ldsAb + bn_);
    STG(pA + (k1 + 131072) + voffA, ldsAb + 16384 + bn_);
    STG(pA + (k1 + 65536) + voffA, ldsAb + 8192 + bn_);
    STG(pA + (k1 + 196608) + voffA, ldsAb + 24576 + bn_);
    STG(pB + k1 + voffB, ldsBb + bn_);
    STG(pB + (k1 + 131072) + voffB, ldsBb + 16384 + bn_);
    STG(pB + (k1 + 32768) + voffB, ldsBb + 4096 + bn_);
    STG(pB + (k1 + 163840) + voffB, ldsBb + 20480 + bn_);

    // m-half 0: 16 reads -> 16 MFMA
    LOADA(0, aEc, aOc)
    LOADB(bF0, 0, bEc, bOc)
    LOADB(bF1, 1, bEc, bOc)
    DOMFMA2(0)

    // m-half 1: 8 reads (reuse aF) -> 16 MFMA; reads drain under half-0 MFMAs
    LOADA(1, aEc, aOc)
    DOMFMA2(1)

    VMCNT0; FENCE; BAR;
  }

  // ---- epilogue: per-row sum(exp) over this 256-col tile + gt extraction ----
  float* red = (float*)lds;
#pragma unroll
  for (int m = 0; m < 8; m++) {
#pragma unroll
    for (int j = 0; j < 4; j++) {
      const int rloc = wm * 128 + m * 16 + hi * 4 + j;
      const int gr = rowBase + rloc;
      const int te = teff[gr];
      float s = 0.f;
#pragma unroll
      for (int n = 0; n < 4; n++) {
        float v = acc[m][n][j];
        const int gc = colBase + wn * 64 + n * 16 + lo;
        if (te == gc) gt[gr] = v;
        s += __expf(v);
      }
#pragma unroll
      for (int d = 1; d < 16; d <<= 1) s += __shfl_xor(s, d);
      if (lo == 0) red[wn * 256 + rloc] = s;
    }
  }
  __syncthreads();
  if (tid < 256) {
    float S = red[tid] + red[256 + tid] + red[512 + tid] + red[768 + tid];
    partial[(size_t)(rowBase + tid) * NTN + by] = S;
  }
}

// ---- combine 125 tile partials per row -> per-token loss ----
__global__ void reduce_lse(const float* __restrict__ partial, const float* __restrict__ gt,
                           const int* __restrict__ ign, const float* __restrict__ divisor,
                           float* __restrict__ pertok) {
  int r = blockIdx.x * 4 + (threadIdx.x >> 6);
  int l = threadIdx.x & 63;
  float S = 0.f;
  for (int p = l; p < NTN; p += 64) S += partial[(size_t)r * NTN + p];
#pragma unroll
  for (int d = 1; d < 64; d <<= 1) S += __shfl_xor(S, d);
  if (l == 0) {
    float lse = __logf(S);
    pertok[r] = ign[r] ? 0.f : (lse - gt[r]) / divisor[0];
  }
}

// ---- deterministic final sum ----
__global__ void final_sum(const float* __restrict__ pertok, float* __restrict__ out) {
  __shared__ float red[16];
  float s = 0.f;
  for (int i = threadIdx.x; i < N_TOK; i += 1024) s += pertok[i];
#pragma unroll
  for (int d = 1; d < 64; d <<= 1) s += __shfl_xor(s, d);
  if ((threadIdx.x & 63) == 0) red[threadIdx.x >> 6] = s;
  __syncthreads();
  if (threadIdx.x == 0) {
    float t = 0.f;
    for (int i = 0; i < 16; i++) t += red[i];
    out[0] = t;
  }
}

extern "C" void kernel_launch(void* const* d_in, const int* in_sizes, int n_in,
                              void* d_out, int out_size, void* d_ws, size_t ws_size,
                              hipStream_t stream) {
  const float* x = (const float*)d_in[0];       // [4096,1024] f32
  const float* w = (const float*)d_in[1];       // [32000,1024] f32
  const int* targ = (const int*)d_in[2];        // [4096] int
  float* out = (float*)d_out;

  char* ws = (char*)d_ws;
  u8*    Xf8     = (u8*)(ws);                      // 4,194,304 B
  u8*    Wf8     = (u8*)(ws + 4194304);            // 32,768,000 B
  float* partial = (float*)(ws + 36962304);        // 2,048,000 B
  float* gt      = (float*)(ws + 39010304);        // 16,384 B
  int*   teff    = (int*)(ws + 39026688);          // 16,384 B
  int*   ign     = (int*)(ws + 39043072);          // 16,384 B
  float* divisor = (float*)(ws + 39059456);        // 256 B
  float* pertok  = (float*)(ws + 39059712);        // 16,384 B

  {
    int n8 = N_TOK * DIM / 8;                      // 524288
    cvt_fp8<<<(n8 + 255) / 256, 256, 0, stream>>>((const float4*)x, (uint2*)Xf8, n8);
  }
  {
    int n8 = NCLS * DIM / 8;                       // 4,096,000
    cvt_fp8<<<(n8 + 255) / 256, 256, 0, stream>>>((const float4*)w, (uint2*)Wf8, n8);
  }
  prep_targ<<<1, 1024, 0, stream>>>(targ, teff, ign, divisor);

  gemm_lse<<<NTM * NTN, 512, 0, stream>>>(Xf8, Wf8, teff, gt, partial);  // 2000 blocks

  reduce_lse<<<N_TOK / 4, 256, 0, stream>>>(partial, gt, ign, divisor, pertok);
  final_sum<<<1, 1024, 0, stream>>>(pertok, out);
}